// Round 4
// baseline (1467.964 us; speedup 1.0000x reference)
//
#include <hip/hip_runtime.h>

#define B_ 2
#define T_ 2048
#define D_ 4096
#define H_ 32
#define KVH_ 8
#define HD_ 128

typedef float f32x4 __attribute__((ext_vector_type(4)));
typedef float f32x2 __attribute__((ext_vector_type(2)));
typedef unsigned int u32x4 __attribute__((ext_vector_type(4)));
typedef unsigned short u16x4 __attribute__((ext_vector_type(4)));
typedef unsigned short u16x2 __attribute__((ext_vector_type(2)));
typedef __bf16 bf16x8 __attribute__((ext_vector_type(8)));

__device__ __forceinline__ unsigned short f2bf(float f) {
  union { float f; unsigned int u; } x; x.f = f;
  unsigned int r = x.u + 0x7fffu + ((x.u >> 16) & 1u);
  return (unsigned short)(r >> 16);
}

__device__ __forceinline__ bf16x8 ldb8(const unsigned short* p) {
  return __builtin_bit_cast(bf16x8, *(const u32x4*)p);
}

__device__ __forceinline__ f32x4 mfma16(bf16x8 a, bf16x8 b, f32x4 c) {
  return __builtin_amdgcn_mfma_f32_16x16x32_bf16(a, b, c, 0, 0, 0);
}

// async global->LDS DMA, 16 B per lane. LDS dest = wave-uniform base + lane*16.
__device__ __forceinline__ void gl_lds16(const void* g, void* l) {
  __builtin_amdgcn_global_load_lds(
      (const __attribute__((address_space(1))) unsigned int*)g,
      (__attribute__((address_space(3))) unsigned int*)l, 16, 0, 0);
}

// ---------------- elementwise f32 -> bf16 cast ----------------
__global__ __launch_bounds__(256) void cast_bf16(const float* __restrict__ src,
                                                 unsigned short* __restrict__ dst, int n4) {
  int i = blockIdx.x * 256 + threadIdx.x;
  if (i >= n4) return;
  f32x4 v = *(const f32x4*)(src + (size_t)i * 4);
  u16x4 o; o.x = f2bf(v.x); o.y = f2bf(v.y); o.z = f2bf(v.z); o.w = f2bf(v.w);
  *(u16x4*)(dst + (size_t)i * 4) = o;
}

// ---------------- C[M,N] = A[M,K] * Bt[N,K]^T, K=4096, bf16 in ----------------
// R2 structure (proven best): 128x128 tile, BK=64, gl_lds width-16 staging with
// XOR swizzle chunk' = chunk ^ (row&7) -> conflict-free ds_read_b128.
// EPI: 0 = fp32 store (wo proj); 1 = RoPE+scale -> Qb head-major bf16;
//      2 = RoPE -> Kb head-major bf16; 3 = bf16 token-major store (v proj).
template <int EPI>
__global__ __launch_bounds__(256) void gemm_bt(const unsigned short* __restrict__ A,
                                               const unsigned short* __restrict__ Bt,
                                               float* __restrict__ Cf,
                                               unsigned short* __restrict__ C16,
                                               const float* __restrict__ fc,
                                               const float* __restrict__ fs, int N) {
  const int m0 = blockIdx.y * 128, n0 = blockIdx.x * 128;
  const int tid = threadIdx.x, lane = tid & 63, wave = tid >> 6;
  const int quad = lane >> 4, l16 = lane & 15;
  const int wy = wave >> 1, wx = wave & 1;
  const int sw = l16 & 7;
  __shared__ unsigned short As[128 * 64];
  __shared__ unsigned short Bs[128 * 64];
  f32x4 acc[4][4];
#pragma unroll
  for (int i = 0; i < 4; ++i)
#pragma unroll
    for (int j = 0; j < 4; ++j) { f32x4 z = {0.f, 0.f, 0.f, 0.f}; acc[i][j] = z; }

  for (int k0 = 0; k0 < 4096; k0 += 64) {
#pragma unroll
    for (int p = 0; p < 4; ++p) {
      int c = p * 256 + tid;
      int row = c >> 3, gc = (c & 7) ^ (row & 7);
      gl_lds16(&A[(size_t)(m0 + row) * 4096 + k0 + gc * 8], &As[c * 8]);
    }
#pragma unroll
    for (int p = 0; p < 4; ++p) {
      int c = p * 256 + tid;
      int row = c >> 3, gc = (c & 7) ^ (row & 7);
      gl_lds16(&Bt[(size_t)(n0 + row) * 4096 + k0 + gc * 8], &Bs[c * 8]);
    }
    __syncthreads();
#pragma unroll
    for (int ks = 0; ks < 2; ++ks) {
      const int cp = ((ks * 4 + quad) ^ sw) * 8;
      bf16x8 af[4], bfr[4];
#pragma unroll
      for (int mt = 0; mt < 4; ++mt) af[mt] = ldb8(&As[(wy * 64 + mt * 16 + l16) * 64 + cp]);
#pragma unroll
      for (int nt = 0; nt < 4; ++nt) bfr[nt] = ldb8(&Bs[(wx * 64 + nt * 16 + l16) * 64 + cp]);
#pragma unroll
      for (int mt = 0; mt < 4; ++mt)
#pragma unroll
        for (int nt = 0; nt < 4; ++nt)
          acc[mt][nt] = mfma16(af[mt], bfr[nt], acc[mt][nt]);
    }
    __syncthreads();
  }

#pragma unroll
  for (int mt = 0; mt < 4; ++mt)
#pragma unroll
    for (int nt = 0; nt < 4; ++nt)
#pragma unroll
      for (int r = 0; r < 4; ++r) {
        int m = m0 + wy * 64 + mt * 16 + quad * 4 + r;
        int n = n0 + wx * 64 + nt * 16 + l16;
        float v = acc[mt][nt][r];
        if constexpr (EPI == 0) {
          Cf[(size_t)m * N + n] = v;
        } else if constexpr (EPI == 3) {
          C16[(size_t)m * N + n] = f2bf(v);
        } else {
          // RoPE: pair (2i,2i+1) sits in adjacent lanes (l16 parity = hd parity)
          int b = m >> 11, t = m & 2047;
          int hh = n >> 7, hd = n & 127;
          float p = __shfl_xor(v, 1);
          int fi = t * 64 + (hd >> 1);
          float c = fc[fi], s = fs[fi];
          float o = (hd & 1) ? (p * s + v * c) : (v * c - p * s);
          if constexpr (EPI == 1) {
            o *= 0.08838834764831845f;  // 1/sqrt(128)
            C16[((size_t)(b * H_ + hh) * T_ + t) * HD_ + hd] = f2bf(o);
          } else {
            C16[((size_t)(b * KVH_ + hh) * T_ + t) * HD_ + hd] = f2bf(o);
          }
        }
      }
}

// ---------------- V: bf16 token-major (B,T,KVH,HD) -> bf16 (B,KVH,HD,T) ----------------
__global__ __launch_bounds__(256) void transpose_v(const unsigned short* __restrict__ vb,
                                                   unsigned short* __restrict__ vt) {
  __shared__ unsigned short tile[64 * 72];   // [hd_local][t_local], padded
  const int hd0 = blockIdx.x * 64;
  const int t0 = blockIdx.y * 64;
  const int bk = blockIdx.z;                 // b*KVH + kvh
  const int b = bk >> 3, kvh = bk & 7;
  const int tid = threadIdx.x;
#pragma unroll
  for (int p = 0; p < 2; ++p) {
    int idx = tid + p * 256;
    int tl = idx >> 3, c8 = (idx & 7) << 3;
    u16x4 lo = *(const u16x4*)&vb[((size_t)(b * T_ + t0 + tl) * KVH_ + kvh) * HD_ + hd0 + c8];
    u16x4 hi = *(const u16x4*)&vb[((size_t)(b * T_ + t0 + tl) * KVH_ + kvh) * HD_ + hd0 + c8 + 4];
#pragma unroll
    for (int j = 0; j < 4; ++j) { tile[(c8 + j) * 72 + tl] = lo[j]; tile[(c8 + 4 + j) * 72 + tl] = hi[j]; }
  }
  __syncthreads();
#pragma unroll
  for (int p = 0; p < 2; ++p) {
    int idx = tid + p * 256;
    int hdl = idx >> 3, c8 = (idx & 7) << 3;
    *(u32x4*)&vt[((size_t)(bk * HD_ + hd0 + hdl)) * T_ + t0 + c8] = *(const u32x4*)&tile[hdl * 72 + c8];
  }
}

// ---------------- Flash attention: no mask, no-max softmax ----------------
// WG = (b,h, 128 q rows); 4 waves x 32 rows. kblock = 64.
// K fragments DIRECT from global (L2-resident) -> no Ks LDS buffer.
// V staged via gl_lds + XOR swizzle (R2-proven). P round-trips padded LDS.
__global__ __launch_bounds__(256, 4) void attn(const unsigned short* __restrict__ Q,
                                               const unsigned short* __restrict__ K,
                                               const unsigned short* __restrict__ Vt,
                                               unsigned short* __restrict__ ctx) {
  const int qb = blockIdx.x;        // 0..15 (128 q-rows each)
  const int bh = blockIdx.y;        // 0..63
  const int b = bh >> 5, h = bh & 31;
  const int kvh = h >> 2;
  const unsigned short* Qh = Q + (size_t)(b * H_ + h) * T_ * HD_;
  const unsigned short* Kh = K + (size_t)(b * KVH_ + kvh) * T_ * HD_;
  const unsigned short* Vh = Vt + (size_t)(b * KVH_ + kvh) * HD_ * T_;
  const int tid = threadIdx.x, lane = tid & 63, wave = tid >> 6;
  const int quad = lane >> 4, l16 = lane & 15;
  const int sw = l16 & 7;
  __shared__ unsigned short Vs[128 * 64];    // [hd][s], unpadded, swizzled
  __shared__ unsigned short Ps[4][32 * 72];  // per-wave P [qrow][s], padded

  const int q0 = qb * 128 + wave * 32;
  bf16x8 qf[2][4];
#pragma unroll
  for (int mt = 0; mt < 2; ++mt)
#pragma unroll
    for (int ks = 0; ks < 4; ++ks)
      qf[mt][ks] = ldb8(&Qh[(size_t)(q0 + mt * 16 + l16) * HD_ + ks * 32 + quad * 8]);

  f32x4 o[2][8];
#pragma unroll
  for (int mt = 0; mt < 2; ++mt)
#pragma unroll
    for (int f = 0; f < 8; ++f) { f32x4 z = {0.f, 0.f, 0.f, 0.f}; o[mt][f] = z; }
  float l_part[2][4] = {{0.f, 0.f, 0.f, 0.f}, {0.f, 0.f, 0.f, 0.f}};

  for (int kb = 0; kb < T_ / 64; ++kb) {
#pragma unroll
    for (int p = 0; p < 4; ++p) {           // V tile: 128 rows x 8 chunks, swizzled
      int c = p * 256 + tid;
      int row = c >> 3, gc = (c & 7) ^ (row & 7);
      gl_lds16(&Vh[(size_t)row * T_ + kb * 64 + gc * 8], &Vs[c * 8]);
    }
    __syncthreads();

    // S(32x64) = Q Kt ; K fragments straight from global (L2)
    f32x4 s[2][4];
#pragma unroll
    for (int mt = 0; mt < 2; ++mt)
#pragma unroll
      for (int nt = 0; nt < 4; ++nt) { f32x4 z = {0.f, 0.f, 0.f, 0.f}; s[mt][nt] = z; }
#pragma unroll
    for (int ks = 0; ks < 4; ++ks) {
#pragma unroll
      for (int nt = 0; nt < 4; ++nt) {
        bf16x8 kf = ldb8(&Kh[(size_t)(kb * 64 + nt * 16 + l16) * HD_ + ks * 32 + quad * 8]);
        s[0][nt] = mfma16(qf[0][ks], kf, s[0][nt]);
        s[1][nt] = mfma16(qf[1][ks], kf, s[1][nt]);
      }
    }

    // no-max softmax: P = exp(s); denominator accumulated per-lane
#pragma unroll
    for (int mt = 0; mt < 2; ++mt)
#pragma unroll
      for (int nt = 0; nt < 4; ++nt)
#pragma unroll
        for (int r = 0; r < 4; ++r) {
          float p_ = __expf(s[mt][nt][r]);
          l_part[mt][r] += p_;
          Ps[wave][(mt * 16 + quad * 4 + r) * 72 + nt * 16 + l16] = f2bf(p_);
        }

    // O += P V
#pragma unroll
    for (int ks2 = 0; ks2 < 2; ++ks2) {
      const int cp = ((ks2 * 4 + quad) ^ sw) * 8;
      bf16x8 pf0 = ldb8(&Ps[wave][(l16) * 72 + ks2 * 32 + quad * 8]);
      bf16x8 pf1 = ldb8(&Ps[wave][(16 + l16) * 72 + ks2 * 32 + quad * 8]);
#pragma unroll
      for (int f = 0; f < 8; ++f) {
        bf16x8 vfr = ldb8(&Vs[(f * 16 + l16) * 64 + cp]);
        o[0][f] = mfma16(pf0, vfr, o[0][f]);
        o[1][f] = mfma16(pf1, vfr, o[1][f]);
      }
    }
    __syncthreads();
  }

  // reduce denominator across the 16 l16 lanes
  float rl[2][4];
#pragma unroll
  for (int mt = 0; mt < 2; ++mt)
#pragma unroll
    for (int r = 0; r < 4; ++r) {
      float l = l_part[mt][r];
      l += __shfl_xor(l, 1);
      l += __shfl_xor(l, 2);
      l += __shfl_xor(l, 4);
      l += __shfl_xor(l, 8);
      rl[mt][r] = 1.0f / l;
    }

  // epilogue: ctx (B,T,H*HD) token-major bf16
#pragma unroll
  for (int mt = 0; mt < 2; ++mt)
#pragma unroll
    for (int f = 0; f < 8; ++f)
#pragma unroll
      for (int r = 0; r < 4; ++r) {
        int t = qb * 128 + wave * 32 + mt * 16 + quad * 4 + r;
        int hd = f * 16 + l16;
        ctx[((size_t)(b * T_ + t)) * D_ + h * HD_ + hd] = f2bf(o[mt][f][r] * rl[mt][r]);
      }
}

extern "C" void kernel_launch(void* const* d_in, const int* in_sizes, int n_in,
                              void* d_out, int out_size, void* d_ws, size_t ws_size,
                              hipStream_t stream) {
  const float* x  = (const float*)d_in[0];
  const float* wq = (const float*)d_in[1];
  const float* wk = (const float*)d_in[2];
  const float* wv = (const float*)d_in[3];
  const float* wo = (const float*)d_in[4];
  const float* fc = (const float*)d_in[5];
  const float* fs = (const float*)d_in[6];
  // start_pos (d_in[7]) == 0 in reference.

  char* ws = (char*)d_ws;
  unsigned short* xb   = (unsigned short*)(ws + 0);          // 33.5 MB bf16 x
  unsigned short* wqb  = (unsigned short*)(ws + 33554432);   // 33.5 MB
  unsigned short* wkb  = (unsigned short*)(ws + 67108864);   // 8.4 MB
  unsigned short* wvb  = (unsigned short*)(ws + 75497472);   // 8.4 MB
  unsigned short* wob  = (unsigned short*)(ws + 83886080);   // 33.5 MB
  unsigned short* ctxb = (unsigned short*)(ws + 117440512);  // 33.5 MB (after vb dead)
  unsigned short* vb   = (unsigned short*)(ws + 134217728);  // 8.4 MB bf16 V token-major
  unsigned short* Qb   = (unsigned short*)(ws + 150994944);  // 33.5 MB bf16 Q head-major
  unsigned short* Kb   = (unsigned short*)(ws + 184549376);  // 8.4 MB bf16 K head-major
  unsigned short* Vtb  = (unsigned short*)(ws + 192937984);  // 8.4 MB bf16 V transposed
  float* out = (float*)d_out;

  cast_bf16<<<16384, 256, 0, stream>>>(x,  xb,  4194304);
  cast_bf16<<<16384, 256, 0, stream>>>(wq, wqb, 4194304);
  cast_bf16<<<4096,  256, 0, stream>>>(wk, wkb, 1048576);
  cast_bf16<<<4096,  256, 0, stream>>>(wv, wvb, 1048576);
  cast_bf16<<<16384, 256, 0, stream>>>(wo, wob, 4194304);

  // Q proj + RoPE + scale -> Qb ; K proj + RoPE -> Kb ; V proj -> vb (bf16)
  gemm_bt<1><<<dim3(32, 32), 256, 0, stream>>>(xb, wqb, nullptr, Qb, fc, fs, 4096);
  gemm_bt<2><<<dim3(8, 32),  256, 0, stream>>>(xb, wkb, nullptr, Kb, fc, fs, 1024);
  gemm_bt<3><<<dim3(8, 32),  256, 0, stream>>>(xb, wvb, nullptr, vb, fc, fs, 1024);

  transpose_v<<<dim3(2, 32, 16), 256, 0, stream>>>(vb, Vtb);

  attn<<<dim3(16, 64), 256, 0, stream>>>(Qb, Kb, Vtb, ctxb);

  gemm_bt<0><<<dim3(32, 32), 256, 0, stream>>>(ctxb, wob, out, nullptr, fc, fs, 4096);
}

// Round 5
// 925.025 us; speedup vs baseline: 1.5869x; 1.5869x over previous
//
#include <hip/hip_runtime.h>

#define B_ 2
#define T_ 2048
#define D_ 4096
#define H_ 32
#define KVH_ 8
#define HD_ 128

typedef float f32x4 __attribute__((ext_vector_type(4)));
typedef float f32x2 __attribute__((ext_vector_type(2)));
typedef unsigned int u32x4 __attribute__((ext_vector_type(4)));
typedef unsigned short u16x4 __attribute__((ext_vector_type(4)));
typedef unsigned short u16x2 __attribute__((ext_vector_type(2)));
typedef __bf16 bf16x8 __attribute__((ext_vector_type(8)));

__device__ __forceinline__ unsigned short f2bf(float f) {
  union { float f; unsigned int u; } x; x.f = f;
  unsigned int r = x.u + 0x7fffu + ((x.u >> 16) & 1u);
  return (unsigned short)(r >> 16);
}

__device__ __forceinline__ bf16x8 ldb8(const unsigned short* p) {
  return __builtin_bit_cast(bf16x8, *(const u32x4*)p);
}

__device__ __forceinline__ f32x4 mfma16(bf16x8 a, bf16x8 b, f32x4 c) {
  return __builtin_amdgcn_mfma_f32_16x16x32_bf16(a, b, c, 0, 0, 0);
}

// async global->LDS DMA, 16 B per lane. LDS dest = wave-uniform base + lane*16.
__device__ __forceinline__ void gl_lds16(const void* g, void* l) {
  __builtin_amdgcn_global_load_lds(
      (const __attribute__((address_space(1))) unsigned int*)g,
      (__attribute__((address_space(3))) unsigned int*)l, 16, 0, 0);
}

// ---------------- elementwise f32 -> bf16 cast ----------------
__global__ __launch_bounds__(256) void cast_bf16(const float* __restrict__ src,
                                                 unsigned short* __restrict__ dst, int n4) {
  int i = blockIdx.x * 256 + threadIdx.x;
  if (i >= n4) return;
  f32x4 v = *(const f32x4*)(src + (size_t)i * 4);
  u16x4 o; o.x = f2bf(v.x); o.y = f2bf(v.y); o.z = f2bf(v.z); o.w = f2bf(v.w);
  *(u16x4*)(dst + (size_t)i * 4) = o;
}

// ---------------- C[M,N] = A[M,K] * Bt[N,K]^T, K=4096, bf16 in ----------------
// R2-proven: 128x128 tile, BK=64, gl_lds width-16 staging with XOR swizzle
// chunk' = chunk ^ (row&7) -> conflict-free ds_read_b128.
// EPI 0: fp32 store (wo proj), C stride N.
// EPI 1: fused QKV epilogue over N=6144: n<4096 Q-rope+scale -> Qb head-major;
//        n<5120 K-rope -> Kb head-major; else V -> vb token-major bf16.
template <int EPI>
__global__ __launch_bounds__(256) void gemm_bt(const unsigned short* __restrict__ A,
                                               const unsigned short* __restrict__ Bt,
                                               float* __restrict__ Cf,
                                               unsigned short* __restrict__ Qb,
                                               unsigned short* __restrict__ Kb,
                                               unsigned short* __restrict__ vb,
                                               const float* __restrict__ fc,
                                               const float* __restrict__ fs, int N) {
  const int m0 = blockIdx.y * 128, n0 = blockIdx.x * 128;
  const int tid = threadIdx.x, lane = tid & 63, wave = tid >> 6;
  const int quad = lane >> 4, l16 = lane & 15;
  const int wy = wave >> 1, wx = wave & 1;
  const int sw = l16 & 7;
  __shared__ unsigned short As[128 * 64];
  __shared__ unsigned short Bs[128 * 64];
  f32x4 acc[4][4];
#pragma unroll
  for (int i = 0; i < 4; ++i)
#pragma unroll
    for (int j = 0; j < 4; ++j) { f32x4 z = {0.f, 0.f, 0.f, 0.f}; acc[i][j] = z; }

  for (int k0 = 0; k0 < 4096; k0 += 64) {
#pragma unroll
    for (int p = 0; p < 4; ++p) {
      int c = p * 256 + tid;
      int row = c >> 3, gc = (c & 7) ^ (row & 7);
      gl_lds16(&A[(size_t)(m0 + row) * 4096 + k0 + gc * 8], &As[c * 8]);
    }
#pragma unroll
    for (int p = 0; p < 4; ++p) {
      int c = p * 256 + tid;
      int row = c >> 3, gc = (c & 7) ^ (row & 7);
      gl_lds16(&Bt[(size_t)(n0 + row) * 4096 + k0 + gc * 8], &Bs[c * 8]);
    }
    __syncthreads();
#pragma unroll
    for (int ks = 0; ks < 2; ++ks) {
      const int cp = ((ks * 4 + quad) ^ sw) * 8;
      bf16x8 af[4], bfr[4];
#pragma unroll
      for (int mt = 0; mt < 4; ++mt) af[mt] = ldb8(&As[(wy * 64 + mt * 16 + l16) * 64 + cp]);
#pragma unroll
      for (int nt = 0; nt < 4; ++nt) bfr[nt] = ldb8(&Bs[(wx * 64 + nt * 16 + l16) * 64 + cp]);
#pragma unroll
      for (int mt = 0; mt < 4; ++mt)
#pragma unroll
        for (int nt = 0; nt < 4; ++nt)
          acc[mt][nt] = mfma16(af[mt], bfr[nt], acc[mt][nt]);
    }
    __syncthreads();
  }

#pragma unroll
  for (int mt = 0; mt < 4; ++mt)
#pragma unroll
    for (int nt = 0; nt < 4; ++nt)
#pragma unroll
      for (int r = 0; r < 4; ++r) {
        int m = m0 + wy * 64 + mt * 16 + quad * 4 + r;
        int n = n0 + wx * 64 + nt * 16 + l16;
        float v = acc[mt][nt][r];
        if constexpr (EPI == 0) {
          Cf[(size_t)m * N + n] = v;
        } else {
          int b = m >> 11, t = m & 2047;
          if (n0 < 4096) {          // Q: rope + scale, head-major
            int hh = n >> 7, hd = n & 127;
            float p = __shfl_xor(v, 1);
            int fi = t * 64 + (hd >> 1);
            float c = fc[fi], s = fs[fi];
            float o = (hd & 1) ? (p * s + v * c) : (v * c - p * s);
            o *= 0.08838834764831845f;  // 1/sqrt(128)
            Qb[((size_t)(b * H_ + hh) * T_ + t) * HD_ + hd] = f2bf(o);
          } else if (n0 < 5120) {   // K: rope, head-major
            int nk = n - 4096;
            int hh = nk >> 7, hd = nk & 127;
            float p = __shfl_xor(v, 1);
            int fi = t * 64 + (hd >> 1);
            float c = fc[fi], s = fs[fi];
            float o = (hd & 1) ? (p * s + v * c) : (v * c - p * s);
            Kb[((size_t)(b * KVH_ + hh) * T_ + t) * HD_ + hd] = f2bf(o);
          } else {                  // V: token-major bf16
            vb[(size_t)m * 1024 + (n - 5120)] = f2bf(v);
          }
        }
      }
}

// ---------------- V: bf16 token-major (B,T,KVH,HD) -> bf16 (B,KVH,HD,T) ----------------
__global__ __launch_bounds__(256) void transpose_v(const unsigned short* __restrict__ vb,
                                                   unsigned short* __restrict__ vt) {
  __shared__ unsigned short tile[64 * 72];   // [hd_local][t_local], padded
  const int hd0 = blockIdx.x * 64;
  const int t0 = blockIdx.y * 64;
  const int bk = blockIdx.z;                 // b*KVH + kvh
  const int b = bk >> 3, kvh = bk & 7;
  const int tid = threadIdx.x;
#pragma unroll
  for (int p = 0; p < 2; ++p) {
    int idx = tid + p * 256;
    int tl = idx >> 3, c8 = (idx & 7) << 3;
    u16x4 lo = *(const u16x4*)&vb[((size_t)(b * T_ + t0 + tl) * KVH_ + kvh) * HD_ + hd0 + c8];
    u16x4 hi = *(const u16x4*)&vb[((size_t)(b * T_ + t0 + tl) * KVH_ + kvh) * HD_ + hd0 + c8 + 4];
#pragma unroll
    for (int j = 0; j < 4; ++j) { tile[(c8 + j) * 72 + tl] = lo[j]; tile[(c8 + 4 + j) * 72 + tl] = hi[j]; }
  }
  __syncthreads();
#pragma unroll
  for (int p = 0; p < 2; ++p) {
    int idx = tid + p * 256;
    int hdl = idx >> 3, c8 = (idx & 7) << 3;
    *(u32x4*)&vt[((size_t)(bk * HD_ + hd0 + hdl)) * T_ + t0 + c8] = *(const u32x4*)&tile[hdl * 72 + c8];
  }
}

// ---------------- Flash attention (R2-proven): no mask, no-max softmax ----------------
// WG = (b,h, 128 q rows); 4 waves x 32 rows. kblock = 64.
// K/V staged via gl_lds + XOR swizzle; P round-trips padded LDS.
__global__ __launch_bounds__(256, 3) void attn(const unsigned short* __restrict__ Q,
                                               const unsigned short* __restrict__ K,
                                               const unsigned short* __restrict__ Vt,
                                               unsigned short* __restrict__ ctx) {
  const int qb = blockIdx.x;        // 0..15 (128 q-rows each)
  const int bh = blockIdx.y;        // 0..63
  const int b = bh >> 5, h = bh & 31;
  const int kvh = h >> 2;
  const unsigned short* Qh = Q + (size_t)(b * H_ + h) * T_ * HD_;
  const unsigned short* Kh = K + (size_t)(b * KVH_ + kvh) * T_ * HD_;
  const unsigned short* Vh = Vt + (size_t)(b * KVH_ + kvh) * HD_ * T_;
  const int tid = threadIdx.x, lane = tid & 63, wave = tid >> 6;
  const int quad = lane >> 4, l16 = lane & 15;
  const int sw = l16 & 7;
  __shared__ unsigned short Ks[64 * 128];    // [kcol][hd], unpadded, swizzled
  __shared__ unsigned short Vs[128 * 64];    // [hd][s],    unpadded, swizzled
  __shared__ unsigned short Ps[4][32 * 72];  // per-wave P [qrow][s], padded

  const int q0 = qb * 128 + wave * 32;
  bf16x8 qf[2][4];
#pragma unroll
  for (int mt = 0; mt < 2; ++mt)
#pragma unroll
    for (int ks = 0; ks < 4; ++ks)
      qf[mt][ks] = ldb8(&Qh[(size_t)(q0 + mt * 16 + l16) * HD_ + ks * 32 + quad * 8]);

  f32x4 o[2][8];
#pragma unroll
  for (int mt = 0; mt < 2; ++mt)
#pragma unroll
    for (int f = 0; f < 8; ++f) { f32x4 z = {0.f, 0.f, 0.f, 0.f}; o[mt][f] = z; }
  float l_part[2][4] = {{0.f, 0.f, 0.f, 0.f}, {0.f, 0.f, 0.f, 0.f}};

  for (int kb = 0; kb < T_ / 64; ++kb) {
#pragma unroll
    for (int p = 0; p < 4; ++p) {           // K tile: 64 rows x 16 chunks
      int c = p * 256 + tid;
      int row = c >> 4, gc = (c & 15) ^ (row & 7);
      gl_lds16(&Kh[(size_t)(kb * 64 + row) * HD_ + gc * 8], &Ks[c * 8]);
    }
#pragma unroll
    for (int p = 0; p < 4; ++p) {           // V tile: 128 rows x 8 chunks
      int c = p * 256 + tid;
      int row = c >> 3, gc = (c & 7) ^ (row & 7);
      gl_lds16(&Vh[(size_t)row * T_ + kb * 64 + gc * 8], &Vs[c * 8]);
    }
    __syncthreads();

    // S(32x64) = Q Kt
    f32x4 s[2][4];
#pragma unroll
    for (int mt = 0; mt < 2; ++mt)
#pragma unroll
      for (int nt = 0; nt < 4; ++nt) { f32x4 z = {0.f, 0.f, 0.f, 0.f}; s[mt][nt] = z; }
#pragma unroll
    for (int ks = 0; ks < 4; ++ks) {
      const int cp = ((ks * 4 + quad) ^ sw) * 8;
#pragma unroll
      for (int nt = 0; nt < 4; ++nt) {
        bf16x8 kf = ldb8(&Ks[(nt * 16 + l16) * 128 + cp]);
        s[0][nt] = mfma16(qf[0][ks], kf, s[0][nt]);
        s[1][nt] = mfma16(qf[1][ks], kf, s[1][nt]);
      }
    }

    // no-max softmax: P = exp(s); denominator accumulated per-lane
#pragma unroll
    for (int mt = 0; mt < 2; ++mt)
#pragma unroll
      for (int nt = 0; nt < 4; ++nt)
#pragma unroll
        for (int r = 0; r < 4; ++r) {
          float p_ = __expf(s[mt][nt][r]);
          l_part[mt][r] += p_;
          Ps[wave][(mt * 16 + quad * 4 + r) * 72 + nt * 16 + l16] = f2bf(p_);
        }

    // O += P V
#pragma unroll
    for (int ks2 = 0; ks2 < 2; ++ks2) {
      const int cp = ((ks2 * 4 + quad) ^ sw) * 8;
      bf16x8 pf0 = ldb8(&Ps[wave][(l16) * 72 + ks2 * 32 + quad * 8]);
      bf16x8 pf1 = ldb8(&Ps[wave][(16 + l16) * 72 + ks2 * 32 + quad * 8]);
#pragma unroll
      for (int f = 0; f < 8; ++f) {
        bf16x8 vfr = ldb8(&Vs[(f * 16 + l16) * 64 + cp]);
        o[0][f] = mfma16(pf0, vfr, o[0][f]);
        o[1][f] = mfma16(pf1, vfr, o[1][f]);
      }
    }
    __syncthreads();
  }

  // reduce denominator across the 16 l16 lanes
  float rl[2][4];
#pragma unroll
  for (int mt = 0; mt < 2; ++mt)
#pragma unroll
    for (int r = 0; r < 4; ++r) {
      float l = l_part[mt][r];
      l += __shfl_xor(l, 1);
      l += __shfl_xor(l, 2);
      l += __shfl_xor(l, 4);
      l += __shfl_xor(l, 8);
      rl[mt][r] = 1.0f / l;
    }

  // epilogue: ctx (B,T,H*HD) token-major bf16
#pragma unroll
  for (int mt = 0; mt < 2; ++mt)
#pragma unroll
    for (int f = 0; f < 8; ++f)
#pragma unroll
      for (int r = 0; r < 4; ++r) {
        int t = qb * 128 + wave * 32 + mt * 16 + quad * 4 + r;
        int hd = f * 16 + l16;
        ctx[((size_t)(b * T_ + t)) * D_ + h * HD_ + hd] = f2bf(o[mt][f][r] * rl[mt][r]);
      }
}

extern "C" void kernel_launch(void* const* d_in, const int* in_sizes, int n_in,
                              void* d_out, int out_size, void* d_ws, size_t ws_size,
                              hipStream_t stream) {
  const float* x  = (const float*)d_in[0];
  const float* wq = (const float*)d_in[1];
  const float* wk = (const float*)d_in[2];
  const float* wv = (const float*)d_in[3];
  const float* wo = (const float*)d_in[4];
  const float* fc = (const float*)d_in[5];
  const float* fs = (const float*)d_in[6];
  // start_pos (d_in[7]) == 0 in reference.

  char* ws = (char*)d_ws;
  unsigned short* xb   = (unsigned short*)(ws + 0);          // 33.5 MB bf16 x
  unsigned short* wqkv = (unsigned short*)(ws + 33554432);   // 50.3 MB [wq;wk;wv] 6144x4096
  unsigned short* wob  = (unsigned short*)(ws + 83886080);   // 33.5 MB
  unsigned short* ctxb = (unsigned short*)(ws + 117440512);  // 33.5 MB (vb dead by attn time)
  unsigned short* vb   = (unsigned short*)(ws + 134217728);  // 8.4 MB bf16 V token-major
  unsigned short* Qb   = (unsigned short*)(ws + 150994944);  // 33.5 MB bf16 Q head-major
  unsigned short* Kb   = (unsigned short*)(ws + 184549376);  // 8.4 MB bf16 K head-major
  unsigned short* Vtb  = (unsigned short*)(ws + 192937984);  // 8.4 MB bf16 V transposed
  float* out = (float*)d_out;

  cast_bf16<<<16384, 256, 0, stream>>>(x,  xb,  4194304);
  cast_bf16<<<16384, 256, 0, stream>>>(wq, wqkv,                       4194304);
  cast_bf16<<<4096,  256, 0, stream>>>(wk, wqkv + (size_t)4096 * 4096, 1048576);
  cast_bf16<<<4096,  256, 0, stream>>>(wv, wqkv + (size_t)5120 * 4096, 1048576);
  cast_bf16<<<16384, 256, 0, stream>>>(wo, wob, 4194304);

  // fused QKV projection + RoPE epilogues
  gemm_bt<1><<<dim3(48, 32), 256, 0, stream>>>(xb, wqkv, nullptr, Qb, Kb, vb, fc, fs, 6144);

  transpose_v<<<dim3(2, 32, 16), 256, 0, stream>>>(vb, Vtb);

  attn<<<dim3(16, 64), 256, 0, stream>>>(Qb, Kb, Vtb, ctxb);

  gemm_bt<0><<<dim3(32, 32), 256, 0, stream>>>(ctxb, wob, out, nullptr, nullptr, nullptr, fc, fs, 4096);
}